// Round 6
// baseline (224.866 us; speedup 1.0000x reference)
//
#include <hip/hip_runtime.h>
#include <stdint.h>

#define EMBED 1024
#define HEAD  256
#define BATCH 8
#define SEQ   2048
#define NTOK  (BATCH*SEQ)

typedef __attribute__((ext_vector_type(8))) short  s16x8;
typedef __attribute__((ext_vector_type(4))) float  f32x4;
typedef __attribute__((ext_vector_type(4))) unsigned short u16x4;

__device__ __forceinline__ unsigned short f2bf(float f) {
  union { float f; uint32_t u; } v; v.f = f;
  return (unsigned short)((v.u + 0x7FFFu + ((v.u >> 16) & 1u)) >> 16);
}

__device__ __forceinline__ void gload_lds16(const void* g, void* l) {
  __builtin_amdgcn_global_load_lds((const __attribute__((address_space(1))) void*)g,
                                   (__attribute__((address_space(3))) void*)l, 16, 0, 0);
}

// ---------------- K0a: transpose weights -> Wt bf16 [3][256 h][1024 e] ----------------
__global__ __launch_bounds__(256) void wt_kernel(const float* __restrict__ Wq,
                                                 const float* __restrict__ Wk,
                                                 const float* __restrict__ Wv,
                                                 unsigned short* __restrict__ Wt) {
  int idx = blockIdx.x * 256 + threadIdx.x;
  int e  = idx & (EMBED - 1);
  int hw = idx >> 10;
  int w  = hw >> 8;
  int h  = hw & 255;
  const float* W = (w == 0) ? Wq : (w == 1) ? Wk : Wv;
  Wt[idx] = f2bf(W[(size_t)e * HEAD + h]);
}

// ---------------- K0b: x fp32 -> xb bf16 (once) ----------------
__global__ __launch_bounds__(256) void xprep_kernel(const float* __restrict__ x,
                                                    unsigned short* __restrict__ xb) {
  size_t i8 = ((size_t)blockIdx.x * 256 + threadIdx.x) * 8;
  f32x4 f0 = *(const f32x4*)(x + i8);
  f32x4 f1 = *(const f32x4*)(x + i8 + 4);
  u16x4 p0, p1;
  #pragma unroll
  for (int j = 0; j < 4; j++) { p0[j] = f2bf(f0[j]); p1[j] = f2bf(f1[j]); }
  *(u16x4*)(xb + i8)     = p0;
  *(u16x4*)(xb + i8 + 4) = p1;
}

// ---------------- K1: QKV projection GEMM (global_load_lds, linear LDS) ----------------
__global__ __launch_bounds__(256) void proj_kernel(const unsigned short* __restrict__ xb,
    const unsigned short* __restrict__ Wt,
    unsigned short* __restrict__ qo, unsigned short* __restrict__ ko,
    unsigned short* __restrict__ vt) {
  __shared__ unsigned short Al[128 * 64];   // linear, 16 KB
  __shared__ unsigned short Bl[128 * 64];   // linear, 16 KB
  const int tid  = threadIdx.x;
  const int lane = tid & 63;
  const int wid  = tid >> 6;
  const int wm = wid >> 1, wn = wid & 1;    // 2x2 waves, each 64x64 out
  const int m0 = blockIdx.x * 128;
  const int n0 = blockIdx.y * 128;
  const int w  = blockIdx.z;
  const unsigned short* Wtw = Wt + (size_t)w * 256 * EMBED;

  f32x4 acc[4][4] = {};

  for (int k0 = 0; k0 < EMBED; k0 += 64) {
    #pragma unroll
    for (int i = 0; i < 4; i++) {
      int u = tid + 256 * i;
      int row = u >> 3, sc = u & 7;
      gload_lds16(xb + (size_t)(m0 + row) * EMBED + k0 + sc * 8,
                  &Al[i * 2048 + wid * 512]);
    }
    #pragma unroll
    for (int i = 0; i < 4; i++) {
      int u = tid + 256 * i;
      int row = u >> 3, sc = u & 7;
      gload_lds16(Wtw + (size_t)(n0 + row) * EMBED + k0 + sc * 8,
                  &Bl[i * 2048 + wid * 512]);
    }
    __syncthreads();
    #pragma unroll
    for (int kk = 0; kk < 2; kk++) {
      s16x8 a[4], b[4];
      #pragma unroll
      for (int mi = 0; mi < 4; mi++) {
        int row = wm * 64 + mi * 16 + (lane & 15);
        a[mi] = *(const s16x8*)(&Al[row * 64 + kk * 32 + 8 * (lane >> 4)]);
      }
      #pragma unroll
      for (int ni = 0; ni < 4; ni++) {
        int row = wn * 64 + ni * 16 + (lane & 15);
        b[ni] = *(const s16x8*)(&Bl[row * 64 + kk * 32 + 8 * (lane >> 4)]);
      }
      #pragma unroll
      for (int mi = 0; mi < 4; mi++)
        #pragma unroll
        for (int ni = 0; ni < 4; ni++)
          acc[mi][ni] = __builtin_amdgcn_mfma_f32_16x16x32_bf16(a[mi], b[ni], acc[mi][ni], 0, 0, 0);
    }
    __syncthreads();
  }

  if (w < 2) {
    unsigned short* dst = (w == 0) ? qo : ko;
    #pragma unroll
    for (int mi = 0; mi < 4; mi++)
      #pragma unroll
      for (int r = 0; r < 4; r++) {
        int mrow = m0 + wm * 64 + mi * 16 + 4 * (lane >> 4) + r;
        #pragma unroll
        for (int ni = 0; ni < 4; ni++) {
          int col = n0 + wn * 64 + ni * 16 + (lane & 15);
          dst[(size_t)mrow * HEAD + col] = f2bf(acc[mi][ni][r]);
        }
      }
  } else {
    #pragma unroll
    for (int mi = 0; mi < 4; mi++) {
      int base = m0 + wm * 64 + mi * 16 + 4 * (lane >> 4);
      #pragma unroll
      for (int ni = 0; ni < 4; ni++) {
        int col = n0 + wn * 64 + ni * 16 + (lane & 15);
        u16x4 pk;
        #pragma unroll
        for (int r = 0; r < 4; r++) pk[r] = f2bf(acc[mi][ni][r]);
        *(u16x4*)(vt + (size_t)col * NTOK + base) = pk;
      }
    }
  }
}

// ---------------- K2: causal flash attention, 2-phase pipelined LDS ----------------
// block = 2 waves x 16 q-rows = 32 rows; KT=32; K via source-swizzled global_load_lds
// (double-buffered); V via reg-stage -> padded LDS (double-buffered). 2 barriers/iter.
__global__ __launch_bounds__(128) void attn_kernel(const unsigned short* __restrict__ qb,
    const unsigned short* __restrict__ kb, const unsigned short* __restrict__ vt,
    float* __restrict__ out) {
  __shared__ unsigned short Kl[2][32 * 256];   // 2 x 16 KB, linear (source-swizzled)
  __shared__ unsigned short Vl[2][256 * 40];   // 2 x 20 KB, stride-40 padded
  __shared__ unsigned short Pl[2][16 * 40];    // per-wave P round-trip
  const int tid  = threadIdx.x;
  const int lane = tid & 63;
  const int wv   = tid >> 6;                   // 0,1
  const int bid = blockIdx.x;
  const int b = bid & 7;                       // batch -> XCD affinity
  const int t = 63 - (bid >> 3);               // LPT: big causal ranges first
  const unsigned short* qB = qb + (size_t)b * SEQ * HEAD;
  const unsigned short* kB = kb + (size_t)b * SEQ * HEAD;
  const unsigned short* vB = vt + (size_t)b * SEQ;
  float* outB = out + (size_t)b * SEQ * HEAD;

  const int rowA = t * 32 + wv * 16 + (lane & 15);
  const int rowD = t * 32 + wv * 16 + 4 * (lane >> 4);

  s16x8 qf[8];
  #pragma unroll
  for (int kf = 0; kf < 8; kf++)
    qf[kf] = *(const s16x8*)(qB + (size_t)rowA * HEAD + kf * 32 + 8 * (lane >> 4));

  f32x4 o[16] = {};
  float m[4], lsum[4];
  #pragma unroll
  for (int r = 0; r < 4; r++) { m[r] = -1e30f; lsum[r] = 0.f; }

  const int nt = t + 1;                        // KT=32 causal tiles
  s16x8 vreg[8];

  // K stage: 1024 x 16B chunks; chunk u -> linear LDS byte u*16; global column
  // pre-swizzled (c_src = c ^ (key&7)) so swizzled reads below see K[key][c].
  #define STAGE_K(buf, j)                                                     \
    _Pragma("unroll")                                                         \
    for (int i = 0; i < 8; i++) {                                             \
      int u = tid + 128 * i;                                                  \
      int key = u >> 5;                                                       \
      int csrc = (u & 31) ^ (key & 7);                                        \
      gload_lds16(kB + (size_t)((j) * 32 + key) * HEAD + csrc * 8,            \
                  &Kl[buf][(i * 128 + wv * 64) * 8]);                         \
    }
  #define LOAD_V(j)                                                           \
    _Pragma("unroll")                                                         \
    for (int i = 0; i < 8; i++) {                                             \
      int u = tid + 128 * i;                                                  \
      vreg[i] = *(const s16x8*)(vB + (size_t)(u >> 2) * NTOK + (j) * 32 + (u & 3) * 8); \
    }
  #define WRITE_V(buf)                                                        \
    _Pragma("unroll")                                                         \
    for (int i = 0; i < 8; i++) {                                             \
      int u = tid + 128 * i;                                                  \
      *(s16x8*)(&Vl[buf][(u >> 2) * 40 + (u & 3) * 8]) = vreg[i];             \
    }

  // prologue: stage tile 0
  STAGE_K(0, 0)
  LOAD_V(0)
  __syncthreads();
  WRITE_V(0)
  __syncthreads();

  for (int j = 0; j < nt; j++) {
    const int cur = j & 1;
    if (j + 1 < nt) {           // block-uniform
      STAGE_K(cur ^ 1, j + 1)
      LOAD_V(j + 1)
    }
    // ---- S = Q K^T from swizzled K LDS ----
    f32x4 s[2] = {};
    #pragma unroll
    for (int n = 0; n < 2; n++) {
      int key = n * 16 + (lane & 15);
      int swz = (key & 7) << 4;
      #pragma unroll
      for (int kf = 0; kf < 8; kf++) {
        s16x8 kfr = *(const s16x8*)((char*)Kl[cur] + ((key * 512 + (lane >> 4) * 16 + kf * 64) ^ swz));
        s[n] = __builtin_amdgcn_mfma_f32_16x16x32_bf16(qf[kf], kfr, s[n], 0, 0, 0);
      }
    }
    const float scale = 0.0625f;
    float mt[4];
    #pragma unroll
    for (int r = 0; r < 4; r++) mt[r] = -1e30f;
    #pragma unroll
    for (int n = 0; n < 2; n++) {
      int key = j * 32 + n * 16 + (lane & 15);
      #pragma unroll
      for (int r = 0; r < 4; r++) {
        float sv = s[n][r] * scale;
        sv = (key > rowD + r) ? -1e30f : sv;
        s[n][r] = sv;
        mt[r] = fmaxf(mt[r], sv);
      }
    }
    #pragma unroll
    for (int r = 0; r < 4; r++) {
      #pragma unroll
      for (int xm = 1; xm < 16; xm <<= 1)
        mt[r] = fmaxf(mt[r], __shfl_xor(mt[r], xm));
      float mn = fmaxf(m[r], mt[r]);
      float al = __expf(m[r] - mn);
      m[r] = mn;
      lsum[r] *= al;
      #pragma unroll
      for (int ht = 0; ht < 16; ht++) o[ht][r] *= al;
    }
    float rs[4] = {0.f, 0.f, 0.f, 0.f};
    #pragma unroll
    for (int n = 0; n < 2; n++)
      #pragma unroll
      for (int r = 0; r < 4; r++) {
        float pv = __expf(s[n][r] - m[r]);
        rs[r] += pv;
        Pl[wv][(4 * (lane >> 4) + r) * 40 + n * 16 + (lane & 15)] = f2bf(pv);
      }
    #pragma unroll
    for (int r = 0; r < 4; r++) {
      #pragma unroll
      for (int xm = 1; xm < 16; xm <<= 1)
        rs[r] += __shfl_xor(rs[r], xm);
      lsum[r] += rs[r];
    }
    s16x8 pa = *(const s16x8*)(&Pl[wv][(lane & 15) * 40 + 8 * (lane >> 4)]);
    // ---- O += P V from padded V LDS ----
    #pragma unroll
    for (int ht = 0; ht < 16; ht++) {
      int h = ht * 16 + (lane & 15);
      s16x8 vf = *(const s16x8*)(&Vl[cur][h * 40 + 8 * (lane >> 4)]);
      o[ht] = __builtin_amdgcn_mfma_f32_16x16x32_bf16(pa, vf, o[ht], 0, 0, 0);
    }
    __syncthreads();            // readers done with bufs[cur]; K[j+1] landed
    if (j + 1 < nt) {
      WRITE_V(cur ^ 1)
    }
    __syncthreads();            // V[j+1] visible to both waves
  }

  #pragma unroll
  for (int ht = 0; ht < 16; ht++) {
    int h = ht * 16 + (lane & 15);
    #pragma unroll
    for (int r = 0; r < 4; r++)
      outB[(size_t)(rowD + r) * HEAD + h] = o[ht][r] / lsum[r];
  }
  #undef STAGE_K
  #undef LOAD_V
  #undef WRITE_V
}

extern "C" void kernel_launch(void* const* d_in, const int* in_sizes, int n_in,
                              void* d_out, int out_size, void* d_ws, size_t ws_size,
                              hipStream_t stream) {
  const float* x  = (const float*)d_in[0];
  const float* Wq = (const float*)d_in[1];
  const float* Wk = (const float*)d_in[2];
  const float* Wv = (const float*)d_in[3];
  float* out = (float*)d_out;

  unsigned short* ws = (unsigned short*)d_ws;
  unsigned short* qb = ws;                          // [16384][256] bf16
  unsigned short* kb = qb + (size_t)NTOK * HEAD;    // [16384][256]
  unsigned short* vt = kb + (size_t)NTOK * HEAD;    // TRANSPOSED [256 h][16384 tok]
  unsigned short* Wt = vt + (size_t)NTOK * HEAD;    // [3][256][1024] bf16
  unsigned short* xb = Wt + (size_t)3 * HEAD * EMBED; // [16384][1024] bf16

  hipLaunchKernelGGL(wt_kernel, dim3(3 * 256 * EMBED / 256), dim3(256), 0, stream,
                     Wq, Wk, Wv, Wt);
  hipLaunchKernelGGL(xprep_kernel, dim3(NTOK * EMBED / (256 * 8)), dim3(256), 0, stream,
                     x, xb);
  hipLaunchKernelGGL(proj_kernel, dim3(128, 2, 3), dim3(256), 0, stream,
                     xb, Wt, qb, kb, vt);
  hipLaunchKernelGGL(attn_kernel, dim3(512), dim3(128), 0, stream,
                     qb, kb, vt, out);
}

// Round 7
// 167.870 us; speedup vs baseline: 1.3395x; 1.3395x over previous
//
#include <hip/hip_runtime.h>
#include <stdint.h>

#define EMBED 1024
#define HEAD  256
#define BATCH 8
#define SEQ   2048
#define NTOK  (BATCH*SEQ)

typedef __attribute__((ext_vector_type(8)))  short  s16x8;
typedef __attribute__((ext_vector_type(4)))  float  f32x4;
typedef __attribute__((ext_vector_type(16))) float  f32x16;
typedef __attribute__((ext_vector_type(4)))  unsigned short u16x4;

__device__ __forceinline__ unsigned short f2bf(float f) {
  union { float f; uint32_t u; } v; v.f = f;
  return (unsigned short)((v.u + 0x7FFFu + ((v.u >> 16) & 1u)) >> 16);
}

__device__ __forceinline__ uint32_t cvtpk(float a, float b) {
  uint32_t r;
  asm("v_cvt_pk_bf16_f32 %0, %1, %2" : "=v"(r) : "v"(a), "v"(b));
  return r;
}

__device__ __forceinline__ void gload_lds16(const void* g, void* l) {
  __builtin_amdgcn_global_load_lds((const __attribute__((address_space(1))) void*)g,
                                   (__attribute__((address_space(3))) void*)l, 16, 0, 0);
}

// ---------------- K0a: weights -> Wt bf16 [3][256 h][1024 e]; fold 1/16 into Wq ----
__global__ __launch_bounds__(256) void wt_kernel(const float* __restrict__ Wq,
                                                 const float* __restrict__ Wk,
                                                 const float* __restrict__ Wv,
                                                 unsigned short* __restrict__ Wt) {
  int idx = blockIdx.x * 256 + threadIdx.x;
  int e  = idx & (EMBED - 1);
  int hw = idx >> 10;
  int w  = hw >> 8;
  int h  = hw & 255;
  const float* W = (w == 0) ? Wq : (w == 1) ? Wk : Wv;
  float sc = (w == 0) ? 0.0625f : 1.0f;     // fold softmax scale into Q projection
  Wt[idx] = f2bf(W[(size_t)e * HEAD + h] * sc);
}

// ---------------- K0b: x fp32 -> xb bf16 (once) ----------------
__global__ __launch_bounds__(256) void xprep_kernel(const float* __restrict__ x,
                                                    unsigned short* __restrict__ xb) {
  size_t i8 = ((size_t)blockIdx.x * 256 + threadIdx.x) * 8;
  f32x4 f0 = *(const f32x4*)(x + i8);
  f32x4 f1 = *(const f32x4*)(x + i8 + 4);
  u16x4 p0, p1;
  #pragma unroll
  for (int j = 0; j < 4; j++) { p0[j] = f2bf(f0[j]); p1[j] = f2bf(f1[j]); }
  *(u16x4*)(xb + i8)     = p0;
  *(u16x4*)(xb + i8 + 4) = p1;
}

// ---------------- K1: QKV projection GEMM (global_load_lds, linear LDS) ------------
__global__ __launch_bounds__(256) void proj_kernel(const unsigned short* __restrict__ xb,
    const unsigned short* __restrict__ Wt,
    unsigned short* __restrict__ qo, unsigned short* __restrict__ ko,
    unsigned short* __restrict__ vt) {
  __shared__ unsigned short Al[128 * 64];
  __shared__ unsigned short Bl[128 * 64];
  const int tid  = threadIdx.x;
  const int lane = tid & 63;
  const int wid  = tid >> 6;
  const int wm = wid >> 1, wn = wid & 1;
  const int m0 = blockIdx.x * 128;
  const int n0 = blockIdx.y * 128;
  const int w  = blockIdx.z;
  const unsigned short* Wtw = Wt + (size_t)w * 256 * EMBED;

  f32x4 acc[4][4] = {};

  for (int k0 = 0; k0 < EMBED; k0 += 64) {
    #pragma unroll
    for (int i = 0; i < 4; i++) {
      int u = tid + 256 * i;
      int row = u >> 3, sc = u & 7;
      gload_lds16(xb + (size_t)(m0 + row) * EMBED + k0 + sc * 8,
                  &Al[i * 2048 + wid * 512]);
    }
    #pragma unroll
    for (int i = 0; i < 4; i++) {
      int u = tid + 256 * i;
      int row = u >> 3, sc = u & 7;
      gload_lds16(Wtw + (size_t)(n0 + row) * EMBED + k0 + sc * 8,
                  &Bl[i * 2048 + wid * 512]);
    }
    __syncthreads();
    #pragma unroll
    for (int kk = 0; kk < 2; kk++) {
      s16x8 a[4], bfr[4];
      #pragma unroll
      for (int mi = 0; mi < 4; mi++) {
        int row = wm * 64 + mi * 16 + (lane & 15);
        a[mi] = *(const s16x8*)(&Al[row * 64 + kk * 32 + 8 * (lane >> 4)]);
      }
      #pragma unroll
      for (int ni = 0; ni < 4; ni++) {
        int row = wn * 64 + ni * 16 + (lane & 15);
        bfr[ni] = *(const s16x8*)(&Bl[row * 64 + kk * 32 + 8 * (lane >> 4)]);
      }
      #pragma unroll
      for (int mi = 0; mi < 4; mi++)
        #pragma unroll
        for (int ni = 0; ni < 4; ni++)
          acc[mi][ni] = __builtin_amdgcn_mfma_f32_16x16x32_bf16(a[mi], bfr[ni], acc[mi][ni], 0, 0, 0);
    }
    __syncthreads();
  }

  if (w < 2) {
    unsigned short* dst = (w == 0) ? qo : ko;
    #pragma unroll
    for (int mi = 0; mi < 4; mi++)
      #pragma unroll
      for (int r = 0; r < 4; r++) {
        int mrow = m0 + wm * 64 + mi * 16 + 4 * (lane >> 4) + r;
        #pragma unroll
        for (int ni = 0; ni < 4; ni++) {
          int col = n0 + wn * 64 + ni * 16 + (lane & 15);
          dst[(size_t)mrow * HEAD + col] = f2bf(acc[mi][ni][r]);
        }
      }
  } else {
    #pragma unroll
    for (int mi = 0; mi < 4; mi++) {
      int base = m0 + wm * 64 + mi * 16 + 4 * (lane >> 4);
      #pragma unroll
      for (int ni = 0; ni < 4; ni++) {
        int col = n0 + wn * 64 + ni * 16 + (lane & 15);
        u16x4 pk;
        #pragma unroll
        for (int r = 0; r < 4; r++) pk[r] = f2bf(acc[mi][ni][r]);
        *(u16x4*)(vt + (size_t)col * NTOK + base) = pk;
      }
    }
  }
}

// ---------------- K2: causal flash attention, 32x32 swapped-operand -----------------
// block = 2 waves, one 32-row q-slab; staged 64-key tiles shared; wave w computes
// keys [j*64+32w, +32); in-lane softmax (q lane-local via S^T); cvt_pk+shfl P
// redistribution; O^T accumulators; end-of-block 2-way merge through LDS.
__global__ __launch_bounds__(128, 1) void attn_kernel(const unsigned short* __restrict__ qb,
    const unsigned short* __restrict__ kb, const unsigned short* __restrict__ vt,
    float* __restrict__ out) {
  __shared__ unsigned short Kl[64 * 256];    // 32 KB, rows 512B, chunk^(key&7) swizzle
  __shared__ unsigned short Vl[256 * 64];    // 32 KB, V^T rows 128B, chunk^(h&7) swizzle
  __shared__ float mls[2][2][32];
  const int tid  = threadIdx.x;
  const int lane = tid & 63;
  const int w    = tid >> 6;                 // 0,1 = key-half
  const int hi   = lane >> 5;
  const int q    = lane & 31;
  const int bid  = blockIdx.x;
  const int b = bid & 7;
  const int t = 63 - (bid >> 3);             // LPT: big causal ranges first
  const unsigned short* qB = qb + (size_t)b * SEQ * HEAD;
  const unsigned short* kB = kb + (size_t)b * SEQ * HEAD;
  const unsigned short* vB = vt + (size_t)b * SEQ;
  float* outB = out + (size_t)b * SEQ * HEAD;
  const int qg = t * 32 + q;                 // this lane's q-row (global)

  // Q^T B-frags in registers: qf[s] = Q[qg][16s + 8hi .. +7]
  s16x8 qf[16];
  #pragma unroll
  for (int s = 0; s < 16; s++)
    qf[s] = *(const s16x8*)(qB + (size_t)qg * HEAD + s * 16 + hi * 8);

  f32x16 o[8] = {};                          // O^T accum: o[ht][reg] = O[h][qg]
  float m = -1e30f, lsum = 0.f;

  const int nt = (t + 2) >> 1;               // 64-key tiles

  for (int j = 0; j < nt; j++) {
    __syncthreads();                         // previous tile's readers done
    // stage K tile 64x256 (2048 x 16B chunks), source pre-swizzled, linear dest
    #pragma unroll
    for (int i = 0; i < 16; i++) {
      int u = tid + 128 * i;
      int key = u >> 5, c = u & 31;
      gload_lds16(kB + (size_t)(j * 64 + key) * HEAD + (c ^ (key & 7)) * 8,
                  &Kl[(i * 128 + w * 64) * 8]);
    }
    // stage V^T tile 256x64
    #pragma unroll
    for (int i = 0; i < 16; i++) {
      int u = tid + 128 * i;
      int h = u >> 3, c8 = u & 7;
      gload_lds16(vB + (size_t)h * NTOK + j * 64 + (c8 ^ (h & 7)) * 8,
                  &Vl[(i * 128 + w * 64) * 8]);
    }
    __syncthreads();                         // staged data visible (vmcnt drained)

    const int kbase = j * 64 + w * 32;
    if (kbase <= t * 32 + 31) {              // wave-uniform: any unmasked key?
      // ---- S^T = K Q^T  (two independent accumulation chains) ----
      f32x16 s0 = {}, s1 = {};
      #pragma unroll
      for (int s = 0; s < 8; s++) {
        s16x8 kf = *(const s16x8*)((const char*)Kl +
                     ((w * 32 + q) * 512 + (((2 * s + hi) ^ (q & 7)) << 4)));
        s0 = __builtin_amdgcn_mfma_f32_32x32x16_bf16(kf, qf[s], s0, 0, 0, 0);
      }
      #pragma unroll
      for (int s = 8; s < 16; s++) {
        s16x8 kf = *(const s16x8*)((const char*)Kl +
                     ((w * 32 + q) * 512 + (((2 * s + hi) ^ (q & 7)) << 4)));
        s1 = __builtin_amdgcn_mfma_f32_32x32x16_bf16(kf, qf[s], s1, 0, 0, 0);
      }
      f32x16 sv;
      #pragma unroll
      for (int r = 0; r < 16; r++) sv[r] = s0[r] + s1[r];

      // ---- causal mask (diagonal tiles only) ----
      if (kbase + 31 > t * 32) {
        #pragma unroll
        for (int r = 0; r < 16; r++) {
          int kg = kbase + (r & 3) + 8 * (r >> 2) + 4 * hi;
          sv[r] = (kg > qg) ? -1e30f : sv[r];
        }
      }
      // ---- row max: in-lane tree + one cross-half shuffle ----
      float mt = sv[0];
      #pragma unroll
      for (int r = 1; r < 16; r++) mt = fmaxf(mt, sv[r]);
      mt = fmaxf(mt, __shfl_xor(mt, 32));
      // ---- defer-max rescale (THR=8) ----
      float mn = fmaxf(m, mt);
      if (!__all(mt - m <= 8.0f)) {
        float al = __expf(m - mn);
        lsum *= al;
        #pragma unroll
        for (int ht = 0; ht < 8; ht++)
          #pragma unroll
          for (int r = 0; r < 16; r++) o[ht][r] *= al;
        m = mn;
      }
      // ---- P = exp(S - m), row sum ----
      #pragma unroll
      for (int r = 0; r < 16; r++) sv[r] = __expf(sv[r] - m);
      float rs = 0.f;
      #pragma unroll
      for (int r = 0; r < 16; r++) rs += sv[r];
      rs += __shfl_xor(rs, 32);
      lsum += rs;
      // ---- P^T B-frags in-register: cvt_pk pairs + cross-half shuffle ----
      uint32_t cc[8], dd[8];
      #pragma unroll
      for (int i = 0; i < 8; i++) cc[i] = cvtpk(sv[2 * i], sv[2 * i + 1]);
      #pragma unroll
      for (int i = 0; i < 8; i++) dd[i] = (uint32_t)__shfl_xor((int)cc[i], 32);
      union { s16x8 v; uint32_t u[4]; } pf0, pf1;
      pf0.u[0] = hi ? dd[2] : cc[0];
      pf0.u[1] = hi ? dd[3] : cc[1];
      pf0.u[2] = hi ? cc[2] : dd[0];
      pf0.u[3] = hi ? cc[3] : dd[1];
      pf1.u[0] = hi ? dd[6] : cc[4];
      pf1.u[1] = hi ? dd[7] : cc[5];
      pf1.u[2] = hi ? cc[6] : dd[4];
      pf1.u[3] = hi ? cc[7] : dd[5];
      // ---- O^T += V^T P^T ----
      #pragma unroll
      for (int ht = 0; ht < 8; ht++) {
        s16x8 vf0 = *(const s16x8*)((const char*)Vl +
                      ((32 * ht + q) * 128 + (((4 * w + hi) ^ (q & 7)) << 4)));
        o[ht] = __builtin_amdgcn_mfma_f32_32x32x16_bf16(vf0, pf0.v, o[ht], 0, 0, 0);
        s16x8 vf1 = *(const s16x8*)((const char*)Vl +
                      ((32 * ht + q) * 128 + (((4 * w + 2 + hi) ^ (q & 7)) << 4)));
        o[ht] = __builtin_amdgcn_mfma_f32_32x32x16_bf16(vf1, pf1.v, o[ht], 0, 0, 0);
      }
    }
  }

  // ---- merge the two key-halves ----
  __syncthreads();
  if (lane < 32) { mls[w][0][q] = m; mls[w][1][q] = lsum; }
  __syncthreads();
  float m0 = mls[0][0][q], m1 = mls[1][0][q];
  float mx = fmaxf(m0, m1);
  float L = __expf(m0 - mx) * mls[0][1][q] + __expf(m1 - mx) * mls[1][1][q];
  float aown = __expf(m - mx);
  #pragma unroll
  for (int ht = 0; ht < 8; ht++)
    #pragma unroll
    for (int r = 0; r < 16; r++) o[ht][r] *= aown;

  float* obuf = (float*)Kl;                  // reuse 32 KB of K LDS
  if (w == 1) {
    #pragma unroll
    for (int ht = 0; ht < 8; ht++)
      #pragma unroll
      for (int g = 0; g < 4; g++) {
        f32x4 v4 = { o[ht][4*g], o[ht][4*g+1], o[ht][4*g+2], o[ht][4*g+3] };
        *(f32x4*)(&obuf[(((ht * 4 + g) * 2 + hi) * 32 + q) * 4]) = v4;
      }
  }
  __syncthreads();
  if (w == 0) {
    #pragma unroll
    for (int ht = 0; ht < 8; ht++)
      #pragma unroll
      for (int g = 0; g < 4; g++) {
        f32x4 v4 = *(const f32x4*)(&obuf[(((ht * 4 + g) * 2 + hi) * 32 + q) * 4]);
        #pragma unroll
        for (int gg = 0; gg < 4; gg++) v4[gg] = (v4[gg] + o[ht][4*g+gg]) / L;
        *(f32x4*)(outB + (size_t)qg * HEAD + ht * 32 + g * 8 + hi * 4) = v4;
      }
  }
}

extern "C" void kernel_launch(void* const* d_in, const int* in_sizes, int n_in,
                              void* d_out, int out_size, void* d_ws, size_t ws_size,
                              hipStream_t stream) {
  const float* x  = (const float*)d_in[0];
  const float* Wq = (const float*)d_in[1];
  const float* Wk = (const float*)d_in[2];
  const float* Wv = (const float*)d_in[3];
  float* out = (float*)d_out;

  unsigned short* ws = (unsigned short*)d_ws;
  unsigned short* qb = ws;                            // [16384][256] bf16 (Q, pre-scaled)
  unsigned short* kb = qb + (size_t)NTOK * HEAD;      // [16384][256]
  unsigned short* vt = kb + (size_t)NTOK * HEAD;      // V^T [256 h][16384 tok]
  unsigned short* Wt = vt + (size_t)NTOK * HEAD;      // [3][256][1024]
  unsigned short* xb = Wt + (size_t)3 * HEAD * EMBED; // [16384][1024]

  hipLaunchKernelGGL(wt_kernel, dim3(3 * 256 * EMBED / 256), dim3(256), 0, stream,
                     Wq, Wk, Wv, Wt);
  hipLaunchKernelGGL(xprep_kernel, dim3(NTOK * EMBED / (256 * 8)), dim3(256), 0, stream,
                     x, xb);
  hipLaunchKernelGGL(proj_kernel, dim3(128, 2, 3), dim3(256), 0, stream,
                     xb, Wt, qb, kb, vt);
  hipLaunchKernelGGL(attn_kernel, dim3(512), dim3(128), 0, stream,
                     qb, kb, vt, out);
}